// Round 18
// baseline (2623.542 us; speedup 1.0000x reference)
//
#include <hip/hip_runtime.h>
#include <stdint.h>

#define NROWS 65536
#define HD 1024

typedef __attribute__((ext_vector_type(8))) short bf16x8;   // 8 bf16 in 4 VGPRs
typedef __attribute__((ext_vector_type(16))) float f32x16;  // MFMA 32x32 accumulator

typedef __attribute__((address_space(1))) const unsigned int* gas_ptr;
typedef __attribute__((address_space(3))) unsigned int* las_ptr;

__device__ __forceinline__ unsigned short f2bf(float f) {
  union { float f; uint32_t u; } v; v.f = f;
  uint32_t u = v.u;
  return (unsigned short)((u + 0x7fffu + ((u >> 16) & 1u)) >> 16);  // RNE
}

__device__ __forceinline__ void gl16(const void* g, void* l) {
  __builtin_amdgcn_global_load_lds((gas_ptr)g, (las_ptr)l, 16, 0, 0);
}

// ---------------- merged prep ----------------
// blocks 0-255:    pack W2 into MFMA-fragment order (R13 layout)
// blocks 256-1279: layer 1 -> h bf16 [65536][1024], granule swizzle (g&3)^((row>>1)&3)
// W2pk granule i: lane=i&63, f=(i>>6)&15 (f=wn*8+cb*4+p*2+kl), T=(i>>10)&15, ct=i>>14.
// col = ct*128+wn*64+cb*32+(lane&31); k = T*64+p*32+kl*16+(lane>>5)*8.
__global__ __launch_bounds__(512) void k_prep(
    const float* __restrict__ x, const float* __restrict__ W1,
    const float* __restrict__ b1, const float* __restrict__ Wmeta,
    const float* __restrict__ bmeta, const float* __restrict__ W2,
    unsigned short* __restrict__ h, unsigned short* __restrict__ W2pk) {
  __shared__ float xs[64 * 12];
  if (blockIdx.x < 256) {   // ---- W2 fragment packing ----
    int i = blockIdx.x * 512 + threadIdx.x;      // 131072 granules
    int lane = i & 63, f = (i >> 6) & 15, T = (i >> 10) & 15, ct = i >> 14;
    int kl = f & 1, p = (f >> 1) & 1, cb = (f >> 2) & 1, wn = f >> 3;
    int col = ct * 128 + wn * 64 + cb * 32 + (lane & 31);
    int k = T * 64 + p * 32 + kl * 16 + (lane >> 5) * 8;
    const float4* s4 = (const float4*)(W2 + (size_t)col * HD + k);
    float4 a = s4[0], b = s4[1];
    uint4 pk;
    pk.x = (uint32_t)f2bf(a.x) | ((uint32_t)f2bf(a.y) << 16);
    pk.y = (uint32_t)f2bf(a.z) | ((uint32_t)f2bf(a.w) << 16);
    pk.z = (uint32_t)f2bf(b.x) | ((uint32_t)f2bf(b.y) << 16);
    pk.w = (uint32_t)f2bf(b.z) | ((uint32_t)f2bf(b.w) << 16);
    *(uint4*)(W2pk + (size_t)i * 8) = pk;
    return;
  }
  // ---- layer 1: h = relu(delta*W1 + b1 + phi*(oh@Wmeta) + oh@bmeta), 64 rows/block ----
  int r0 = ((int)blockIdx.x - 256) * 64;
  int t = threadIdx.x;
  int j0 = t * 2;
  float w1a = W1[j0], w1b = W1[j0 + 1];
  float b1a = b1[j0], b1b = b1[j0 + 1];
  float wma[10], wmb[10], bma[10], bmb[10];
#pragma unroll
  for (int e = 0; e < 10; e++) {
    float2 wmv = *(const float2*)(Wmeta + e * HD + j0);
    float2 bmv = *(const float2*)(bmeta + e * HD + j0);
    wma[e] = wmv.x; wmb[e] = wmv.y; bma[e] = bmv.x; bmb[e] = bmv.y;
  }
  for (int i = t; i < 64 * 12; i += 512) xs[i] = x[(size_t)r0 * 12 + i];
  __syncthreads();
  int g = j0 >> 3;
  for (int r = 0; r < 64; r++) {
    const float* xr = xs + r * 12;
    float delta = xr[10], phi = xr[11];
    float s1a = 0.f, s1b = 0.f, s2a = 0.f, s2b = 0.f;
#pragma unroll
    for (int e = 0; e < 10; e++) {
      float oh = xr[e];
      s1a = fmaf(oh, wma[e], s1a);
      s1b = fmaf(oh, wmb[e], s1b);
      s2a = fmaf(oh, bma[e], s2a);
      s2b = fmaf(oh, bmb[e], s2b);
    }
    float pa = fmaf(delta, w1a, b1a) + fmaf(phi, s1a, s2a);
    float pb = fmaf(delta, w1b, b1b) + fmaf(phi, s1b, s2b);
    pa = fmaxf(pa, 0.f); pb = fmaxf(pb, 0.f);
    uint32_t pk = (uint32_t)f2bf(pa) | ((uint32_t)f2bf(pb) << 16);
    int rr = r0 + r;
    int gs = (g & 124) | ((g & 3) ^ ((rr >> 1) & 3));
    *(uint32_t*)(h + (size_t)rr * HD + gs * 8 + (j0 & 7)) = pk;
  }
}

// ---------------- layers 2+3: R13 main loop; 16 KB LDS; 6 blocks/CU; in-wave epilogue ----------------
// grid 4096 (XCD-swizzled) = 512 rt x 8 ct; 256 threads = 4 waves (2x2), wave tile 64x64
// = 2x2 of 32x32x16 bf16 MFMA (acc 64 AGPR). LDS holds ONLY A (16 KB staging) ->
// 6 blocks/CU (96 KB LDS, 24 waves/CU, VGPR 60 <= 85 budget at 6 waves/SIMD).
// Per K-tile(64): {8 B-frag loads -> regs (coalesced, L2-resident W2pk) | 4 gl_lds A |
//   __syncthreads | 8 ds_read_b128 (A frags) + 16 MFMA | __syncthreads}.
// Epilogue: fully in-wave (shfl over l31 covers the wave's 64 cols, both halves emit
// their own rows); per-(ct,wn) partial slice -> no cross-wave LDS, no atomics.
__global__ __launch_bounds__(256, 6) void k_gemm(
    const unsigned short* __restrict__ h, const unsigned short* __restrict__ W2pk,
    const float* __restrict__ b2, const float* __restrict__ W3,
    float* __restrict__ partial) {
  __shared__ char lds[16384];   // A panels @0/8192
  int tid = threadIdx.x;
  // XCD swizzle: 4096 blocks = 8 XCDs x 512; XCD k gets contiguous logical range.
  int b = (int)blockIdx.x;
  int bx = ((b & 7) << 9) | (b >> 3);
  int rt = bx >> 3, ct = bx & 7;   // 8 consecutive bx share rt -> A-panel L2 reuse
  size_t r0 = (size_t)rt * 128;
  int c0 = ct * 128;
  int w = tid >> 6, lane = tid & 63;
  int wm = w >> 1, wn = w & 1;
  int l31 = lane & 31, hi = lane >> 5;
  int sw = (l31 >> 1) & 3;   // A granule swizzle key (row bases are multiples of 32)

  f32x16 acc[2][2];
#pragma unroll
  for (int rb = 0; rb < 2; rb++)
#pragma unroll
    for (int cb = 0; cb < 2; cb++)
#pragma unroll
      for (int i = 0; i < 16; i++) acc[rb][cb][i] = 0.f;

  int arow0 = (wm * 64 + 0  + l31) * 64;
  int arow1 = (wm * 64 + 32 + l31) * 64;
  // per-wave packed-B base for this ct: frags (cb,p,kl) at (cb*4+p*2+kl)*512 elements
  const unsigned short* bwave = W2pk + ((size_t)ct * 16 * 16 + (size_t)wn * 8) * 512 + lane * 8;

  for (int T = 0; T < 16; T++) {
    // 1) B fragments straight to registers (8 coalesced 1KB wave-loads, L2 hits)
    const unsigned short* bt = bwave + (size_t)T * 16 * 512;
    bf16x8 B[2][4];   // [cb][p*2+kl]
#pragma unroll
    for (int cb = 0; cb < 2; cb++)
#pragma unroll
      for (int pk = 0; pk < 4; pk++)
        B[cb][pk] = *(const bf16x8*)(bt + (cb * 4 + pk) * 512);
    // 2) stage A tile (panels p0@0, p1@8192; dest lane-linear; source pre-swizzled)
#pragma unroll
    for (int q = 0; q < 2; q++) {
      int s = tid + 256 * q;            // 0..511
      int row = s >> 2, g4 = s & 3;
      const unsigned short* hsrc = h + (r0 + row) * (size_t)HD + T * 64 + g4 * 8;
      gl16(hsrc,      lds +        (size_t)s * 16);
      gl16(hsrc + 32, lds + 8192 + (size_t)s * 16);
    }
    __syncthreads();   // drains vmcnt: A tile + B regs ready; prior A reads done
    // 3) A frag reads + MFMA (B from registers)
#pragma unroll
    for (int p = 0; p < 2; p++) {
      const char* lA = lds + p * 8192;
#pragma unroll
      for (int kl = 0; kl < 2; kl++) {
        int slot = ((kl * 2 + hi) ^ sw) << 4;
        bf16x8 a0 = *(const bf16x8*)(lA + arow0 + slot);
        bf16x8 a1 = *(const bf16x8*)(lA + arow1 + slot);
        acc[0][0] = __builtin_amdgcn_mfma_f32_32x32x16_bf16(a0, B[0][p * 2 + kl], acc[0][0], 0, 0, 0);
        acc[0][1] = __builtin_amdgcn_mfma_f32_32x32x16_bf16(a0, B[1][p * 2 + kl], acc[0][1], 0, 0, 0);
        acc[1][0] = __builtin_amdgcn_mfma_f32_32x32x16_bf16(a1, B[0][p * 2 + kl], acc[1][0], 0, 0, 0);
        acc[1][1] = __builtin_amdgcn_mfma_f32_32x32x16_bf16(a1, B[1][p * 2 + kl], acc[1][1], 0, 0, 0);
      }
    }
    __syncthreads();
  }

  // ---- epilogue: v = relu(acc+b2); o = v x W3^T; in-wave shfl reduce; per-(ct,wn) slice ----
  float b2c[2], w30[2], w31[2];
#pragma unroll
  for (int cb = 0; cb < 2; cb++) {
    int c = c0 + wn * 64 + cb * 32 + l31;
    b2c[cb] = b2[c];
    w30[cb] = W3[c];
    w31[cb] = W3[HD + c];
  }
  float* ps = partial + (size_t)(ct * 2 + wn) * (NROWS * 2);
#pragma unroll
  for (int rb = 0; rb < 2; rb++) {
#pragma unroll
    for (int reg = 0; reg < 16; reg++) {
      float v0 = fmaxf(acc[rb][0][reg] + b2c[0], 0.f);
      float v1 = fmaxf(acc[rb][1][reg] + b2c[1], 0.f);
      float o0 = fmaf(v0, w30[0], v1 * w30[1]);   // covers both cb blocks (64 cols/lane-set)
      float o1 = fmaf(v0, w31[0], v1 * w31[1]);
#pragma unroll
      for (int m = 1; m <= 16; m <<= 1) {  // reduce over l31; masks <32 keep halves apart
        o0 += __shfl_xor(o0, m);
        o1 += __shfl_xor(o1, m);
      }
      if (l31 == 0) {   // each 32-lane half emits its own rows (rowf depends on hi)
        size_t row = r0 + wm * 64 + rb * 32 + (reg & 3) + 8 * (reg >> 2) + 4 * hi;  // C/D map
        float2 o; o.x = o0; o.y = o1;
        *(float2*)(ps + row * 2) = o;
      }
    }
  }
}

// ---------------- final: out = b3 + sum over 16 partial slices ----------------
__global__ void k_reduce(const float* __restrict__ partial, const float* __restrict__ b3,
                         float* __restrict__ out) {
  int i = blockIdx.x * 256 + threadIdx.x;  // 131072
  float s = b3[i & 1];
#pragma unroll
  for (int sl = 0; sl < 16; sl++) s += partial[(size_t)sl * 131072 + i];
  out[i] = s;
}

extern "C" void kernel_launch(void* const* d_in, const int* in_sizes, int n_in,
                              void* d_out, int out_size, void* d_ws, size_t ws_size,
                              hipStream_t stream) {
  const float* x     = (const float*)d_in[0];
  const float* W1    = (const float*)d_in[1];
  const float* b1    = (const float*)d_in[2];
  const float* Wmeta = (const float*)d_in[3];
  const float* bmeta = (const float*)d_in[4];
  const float* W2    = (const float*)d_in[5];
  const float* b2    = (const float*)d_in[6];
  const float* W3    = (const float*)d_in[7];
  const float* b3    = (const float*)d_in[8];
  float* out = (float*)d_out;

  char* ws = (char*)d_ws;
  unsigned short* hbuf  = (unsigned short*)ws;                              // 128 MiB
  unsigned short* W2pk  = (unsigned short*)(ws + (size_t)NROWS * HD * 2);   // 2 MiB
  float* partial = (float*)(ws + (size_t)NROWS * HD * 2 + (size_t)HD * HD * 2);  // 8 MiB (16 slices)

  k_prep<<<1280, 512, 0, stream>>>(x, W1, b1, Wmeta, bmeta, W2, hbuf, W2pk);
  k_gemm<<<4096, 256, 0, stream>>>(hbuf, W2pk, b2, W3, partial);
  k_reduce<<<512, 256, 0, stream>>>(partial, b3, out);
}

// Round 19
// 223.662 us; speedup vs baseline: 11.7299x; 11.7299x over previous
//
#include <hip/hip_runtime.h>
#include <stdint.h>

#define NROWS 65536
#define HD 1024

typedef __attribute__((ext_vector_type(8))) short bf16x8;   // 8 bf16 in 4 VGPRs
typedef __attribute__((ext_vector_type(16))) float f32x16;  // MFMA 32x32 accumulator

typedef __attribute__((address_space(1))) const unsigned int* gas_ptr;
typedef __attribute__((address_space(3))) unsigned int* las_ptr;

__device__ __forceinline__ unsigned short f2bf(float f) {
  union { float f; uint32_t u; } v; v.f = f;
  uint32_t u = v.u;
  return (unsigned short)((u + 0x7fffu + ((u >> 16) & 1u)) >> 16);  // RNE
}

__device__ __forceinline__ void gl16(const void* g, void* l) {
  __builtin_amdgcn_global_load_lds((gas_ptr)g, (las_ptr)l, 16, 0, 0);
}

// ---------------- merged prep ----------------
// blocks 0-255:    pack W2 into MFMA-fragment order (R13 layout)
// blocks 256-1279: layer 1 -> h bf16 [65536][1024], granule swizzle (g&3)^((row>>1)&3)
// W2pk granule i: lane=i&63, f=(i>>6)&15 (f=wn*8+cb*4+p*2+kl), T=(i>>10)&15, ct=i>>14.
// col = ct*128+wn*64+cb*32+(lane&31); k = T*64+p*32+kl*16+(lane>>5)*8.
__global__ __launch_bounds__(512) void k_prep(
    const float* __restrict__ x, const float* __restrict__ W1,
    const float* __restrict__ b1, const float* __restrict__ Wmeta,
    const float* __restrict__ bmeta, const float* __restrict__ W2,
    unsigned short* __restrict__ h, unsigned short* __restrict__ W2pk) {
  __shared__ float xs[64 * 12];
  if (blockIdx.x < 256) {   // ---- W2 fragment packing ----
    int i = blockIdx.x * 512 + threadIdx.x;      // 131072 granules
    int lane = i & 63, f = (i >> 6) & 15, T = (i >> 10) & 15, ct = i >> 14;
    int kl = f & 1, p = (f >> 1) & 1, cb = (f >> 2) & 1, wn = f >> 3;
    int col = ct * 128 + wn * 64 + cb * 32 + (lane & 31);
    int k = T * 64 + p * 32 + kl * 16 + (lane >> 5) * 8;
    const float4* s4 = (const float4*)(W2 + (size_t)col * HD + k);
    float4 a = s4[0], b = s4[1];
    uint4 pk;
    pk.x = (uint32_t)f2bf(a.x) | ((uint32_t)f2bf(a.y) << 16);
    pk.y = (uint32_t)f2bf(a.z) | ((uint32_t)f2bf(a.w) << 16);
    pk.z = (uint32_t)f2bf(b.x) | ((uint32_t)f2bf(b.y) << 16);
    pk.w = (uint32_t)f2bf(b.z) | ((uint32_t)f2bf(b.w) << 16);
    *(uint4*)(W2pk + (size_t)i * 8) = pk;
    return;
  }
  // ---- layer 1: h = relu(delta*W1 + b1 + phi*(oh@Wmeta) + oh@bmeta), 64 rows/block ----
  int r0 = ((int)blockIdx.x - 256) * 64;
  int t = threadIdx.x;
  int j0 = t * 2;
  float w1a = W1[j0], w1b = W1[j0 + 1];
  float b1a = b1[j0], b1b = b1[j0 + 1];
  float wma[10], wmb[10], bma[10], bmb[10];
#pragma unroll
  for (int e = 0; e < 10; e++) {
    float2 wmv = *(const float2*)(Wmeta + e * HD + j0);
    float2 bmv = *(const float2*)(bmeta + e * HD + j0);
    wma[e] = wmv.x; wmb[e] = wmv.y; bma[e] = bmv.x; bmb[e] = bmv.y;
  }
  for (int i = t; i < 64 * 12; i += 512) xs[i] = x[(size_t)r0 * 12 + i];
  __syncthreads();
  int g = j0 >> 3;
  for (int r = 0; r < 64; r++) {
    const float* xr = xs + r * 12;
    float delta = xr[10], phi = xr[11];
    float s1a = 0.f, s1b = 0.f, s2a = 0.f, s2b = 0.f;
#pragma unroll
    for (int e = 0; e < 10; e++) {
      float oh = xr[e];
      s1a = fmaf(oh, wma[e], s1a);
      s1b = fmaf(oh, wmb[e], s1b);
      s2a = fmaf(oh, bma[e], s2a);
      s2b = fmaf(oh, bmb[e], s2b);
    }
    float pa = fmaf(delta, w1a, b1a) + fmaf(phi, s1a, s2a);
    float pb = fmaf(delta, w1b, b1b) + fmaf(phi, s1b, s2b);
    pa = fmaxf(pa, 0.f); pb = fmaxf(pb, 0.f);
    uint32_t pk = (uint32_t)f2bf(pa) | ((uint32_t)f2bf(pb) << 16);
    int rr = r0 + r;
    int gs = (g & 124) | ((g & 3) ^ ((rr >> 1) & 3));
    *(uint32_t*)(h + (size_t)rr * HD + gs * 8 + (j0 & 7)) = pk;
  }
}

// ---------------- layers 2+3: R13 main loop verbatim (4 waves/SIMD = natural max for
// a 64-AGPR accumulator: unified need 124, 512/124 = 4); in-wave epilogue ----------------
// grid 4096 (XCD-swizzled) = 512 rt x 8 ct; 256 threads = 4 waves (2x2), wave tile 64x64
// = 2x2 of 32x32x16 bf16 MFMA. LDS holds ONLY A (16 KB staging).
// Per K-tile(64): {8 B-frag loads -> regs (coalesced, L2-resident W2pk) | 4 gl_lds A |
//   __syncthreads | 8 ds_read_b128 (A frags) + 16 MFMA | __syncthreads}.
// Epilogue: fully in-wave shfl (no LDS, no atomics); per-(ct,wn) partial slice.
__global__ __launch_bounds__(256, 4) void k_gemm(
    const unsigned short* __restrict__ h, const unsigned short* __restrict__ W2pk,
    const float* __restrict__ b2, const float* __restrict__ W3,
    float* __restrict__ partial) {
  __shared__ char lds[16384];   // A panels @0/8192
  int tid = threadIdx.x;
  // XCD swizzle: 4096 blocks = 8 XCDs x 512; XCD k gets contiguous logical range.
  int b = (int)blockIdx.x;
  int bx = ((b & 7) << 9) | (b >> 3);
  int rt = bx >> 3, ct = bx & 7;   // 8 consecutive bx share rt -> A-panel L2 reuse
  size_t r0 = (size_t)rt * 128;
  int c0 = ct * 128;
  int w = tid >> 6, lane = tid & 63;
  int wm = w >> 1, wn = w & 1;
  int l31 = lane & 31, hi = lane >> 5;
  int sw = (l31 >> 1) & 3;   // A granule swizzle key (row bases are multiples of 32)

  f32x16 acc[2][2];
#pragma unroll
  for (int rb = 0; rb < 2; rb++)
#pragma unroll
    for (int cb = 0; cb < 2; cb++)
#pragma unroll
      for (int i = 0; i < 16; i++) acc[rb][cb][i] = 0.f;

  int arow0 = (wm * 64 + 0  + l31) * 64;
  int arow1 = (wm * 64 + 32 + l31) * 64;
  // per-wave packed-B base for this ct: frags (cb,p,kl) at (cb*4+p*2+kl)*512 elements
  const unsigned short* bwave = W2pk + ((size_t)ct * 16 * 16 + (size_t)wn * 8) * 512 + lane * 8;

  for (int T = 0; T < 16; T++) {
    // 1) B fragments straight to registers (8 coalesced 1KB wave-loads, L2 hits)
    const unsigned short* bt = bwave + (size_t)T * 16 * 512;
    bf16x8 B[2][4];   // [cb][p*2+kl]
#pragma unroll
    for (int cb = 0; cb < 2; cb++)
#pragma unroll
      for (int pk = 0; pk < 4; pk++)
        B[cb][pk] = *(const bf16x8*)(bt + (cb * 4 + pk) * 512);
    // 2) stage A tile (panels p0@0, p1@8192; dest lane-linear; source pre-swizzled)
#pragma unroll
    for (int q = 0; q < 2; q++) {
      int s = tid + 256 * q;            // 0..511
      int row = s >> 2, g4 = s & 3;
      const unsigned short* hsrc = h + (r0 + row) * (size_t)HD + T * 64 + g4 * 8;
      gl16(hsrc,      lds +        (size_t)s * 16);
      gl16(hsrc + 32, lds + 8192 + (size_t)s * 16);
    }
    __syncthreads();   // drains vmcnt: A tile + B regs ready; prior A reads done
    // 3) A frag reads + MFMA (B from registers)
#pragma unroll
    for (int p = 0; p < 2; p++) {
      const char* lA = lds + p * 8192;
#pragma unroll
      for (int kl = 0; kl < 2; kl++) {
        int slot = ((kl * 2 + hi) ^ sw) << 4;
        bf16x8 a0 = *(const bf16x8*)(lA + arow0 + slot);
        bf16x8 a1 = *(const bf16x8*)(lA + arow1 + slot);
        acc[0][0] = __builtin_amdgcn_mfma_f32_32x32x16_bf16(a0, B[0][p * 2 + kl], acc[0][0], 0, 0, 0);
        acc[0][1] = __builtin_amdgcn_mfma_f32_32x32x16_bf16(a0, B[1][p * 2 + kl], acc[0][1], 0, 0, 0);
        acc[1][0] = __builtin_amdgcn_mfma_f32_32x32x16_bf16(a1, B[0][p * 2 + kl], acc[1][0], 0, 0, 0);
        acc[1][1] = __builtin_amdgcn_mfma_f32_32x32x16_bf16(a1, B[1][p * 2 + kl], acc[1][1], 0, 0, 0);
      }
    }
    __syncthreads();
  }

  // ---- epilogue: v = relu(acc+b2); o = v x W3^T; in-wave shfl reduce; per-(ct,wn) slice ----
  float b2c[2], w30[2], w31[2];
#pragma unroll
  for (int cb = 0; cb < 2; cb++) {
    int c = c0 + wn * 64 + cb * 32 + l31;
    b2c[cb] = b2[c];
    w30[cb] = W3[c];
    w31[cb] = W3[HD + c];
  }
  float* ps = partial + (size_t)(ct * 2 + wn) * (NROWS * 2);
#pragma unroll
  for (int rb = 0; rb < 2; rb++) {
#pragma unroll
    for (int reg = 0; reg < 16; reg++) {
      float v0 = fmaxf(acc[rb][0][reg] + b2c[0], 0.f);
      float v1 = fmaxf(acc[rb][1][reg] + b2c[1], 0.f);
      float o0 = fmaf(v0, w30[0], v1 * w30[1]);   // covers both cb blocks (64 cols/lane-set)
      float o1 = fmaf(v0, w31[0], v1 * w31[1]);
#pragma unroll
      for (int m = 1; m <= 16; m <<= 1) {  // reduce over l31; masks <32 keep halves apart
        o0 += __shfl_xor(o0, m);
        o1 += __shfl_xor(o1, m);
      }
      if (l31 == 0) {   // each 32-lane half emits its own rows (rowf depends on hi)
        size_t row = r0 + wm * 64 + rb * 32 + (reg & 3) + 8 * (reg >> 2) + 4 * hi;  // C/D map
        float2 o; o.x = o0; o.y = o1;
        *(float2*)(ps + row * 2) = o;
      }
    }
  }
}

// ---------------- final: out = b3 + sum over 16 partial slices ----------------
__global__ void k_reduce(const float* __restrict__ partial, const float* __restrict__ b3,
                         float* __restrict__ out) {
  int i = blockIdx.x * 256 + threadIdx.x;  // 131072
  float s = b3[i & 1];
#pragma unroll
  for (int sl = 0; sl < 16; sl++) s += partial[(size_t)sl * 131072 + i];
  out[i] = s;
}

extern "C" void kernel_launch(void* const* d_in, const int* in_sizes, int n_in,
                              void* d_out, int out_size, void* d_ws, size_t ws_size,
                              hipStream_t stream) {
  const float* x     = (const float*)d_in[0];
  const float* W1    = (const float*)d_in[1];
  const float* b1    = (const float*)d_in[2];
  const float* Wmeta = (const float*)d_in[3];
  const float* bmeta = (const float*)d_in[4];
  const float* W2    = (const float*)d_in[5];
  const float* b2    = (const float*)d_in[6];
  const float* W3    = (const float*)d_in[7];
  const float* b3    = (const float*)d_in[8];
  float* out = (float*)d_out;

  char* ws = (char*)d_ws;
  unsigned short* hbuf  = (unsigned short*)ws;                              // 128 MiB
  unsigned short* W2pk  = (unsigned short*)(ws + (size_t)NROWS * HD * 2);   // 2 MiB
  float* partial = (float*)(ws + (size_t)NROWS * HD * 2 + (size_t)HD * HD * 2);  // 8 MiB (16 slices)

  k_prep<<<1280, 512, 0, stream>>>(x, W1, b1, Wmeta, bmeta, W2, hbuf, W2pk);
  k_gemm<<<4096, 256, 0, stream>>>(hbuf, W2pk, b2, W3, partial);
  k_reduce<<<512, 256, 0, stream>>>(partial, b3, out);
}

// Round 20
// 206.180 us; speedup vs baseline: 12.7245x; 1.0848x over previous
//
#include <hip/hip_runtime.h>
#include <stdint.h>

#define NROWS 65536
#define HD 1024

typedef __attribute__((ext_vector_type(8))) short bf16x8;   // 8 bf16 in 4 VGPRs
typedef __attribute__((ext_vector_type(16))) float f32x16;  // MFMA 32x32 accumulator

typedef __attribute__((address_space(1))) const unsigned int* gas_ptr;
typedef __attribute__((address_space(3))) unsigned int* las_ptr;

__device__ __forceinline__ unsigned short f2bf(float f) {
  union { float f; uint32_t u; } v; v.f = f;
  uint32_t u = v.u;
  return (unsigned short)((u + 0x7fffu + ((u >> 16) & 1u)) >> 16);  // RNE
}

__device__ __forceinline__ void gl16(const void* g, void* l) {
  __builtin_amdgcn_global_load_lds((gas_ptr)g, (las_ptr)l, 16, 0, 0);
}

// ---------------- prep: W2 fp32 -> bf16 packed in MFMA-fragment order ----------------
// W2pk granule i (16B): lane=i&63, f=(i>>6)&15, T=(i>>10)&15, ct=i>>14;
// f = wn*8 + cb*4 + p*2 + kl. Source: col = ct*128+wn*64+cb*32+(lane&31),
// k = T*64 + p*32 + kl*16 + (lane>>5)*8. A wave's frag load is 64x16B contiguous.
__global__ void k_w2pk(const float* __restrict__ W2, unsigned short* __restrict__ W2pk) {
  int i = blockIdx.x * 256 + threadIdx.x;   // 131072 granules
  int lane = i & 63, f = (i >> 6) & 15, T = (i >> 10) & 15, ct = i >> 14;
  int kl = f & 1, p = (f >> 1) & 1, cb = (f >> 2) & 1, wn = f >> 3;
  int col = ct * 128 + wn * 64 + cb * 32 + (lane & 31);
  int k = T * 64 + p * 32 + kl * 16 + (lane >> 5) * 8;
  const float4* s4 = (const float4*)(W2 + (size_t)col * HD + k);
  float4 a = s4[0], b = s4[1];
  uint4 pk;
  pk.x = (uint32_t)f2bf(a.x) | ((uint32_t)f2bf(a.y) << 16);
  pk.y = (uint32_t)f2bf(a.z) | ((uint32_t)f2bf(a.w) << 16);
  pk.z = (uint32_t)f2bf(b.x) | ((uint32_t)f2bf(b.y) << 16);
  pk.w = (uint32_t)f2bf(b.z) | ((uint32_t)f2bf(b.w) << 16);
  *(uint4*)(W2pk + (size_t)i * 8) = pk;
}

// ---------------- layer 1: h bf16 [65536][1024], granule swizzle (g&3)^((row>>1)&3) ----------------
__global__ __launch_bounds__(512) void k_layer1(
    const float* __restrict__ x, const float* __restrict__ W1,
    const float* __restrict__ b1, const float* __restrict__ Wmeta,
    const float* __restrict__ bmeta, unsigned short* __restrict__ h) {
  __shared__ float xs[64 * 12];
  int r0 = blockIdx.x * 64;
  int t = threadIdx.x;
  int j0 = t * 2;
  float w1a = W1[j0], w1b = W1[j0 + 1];
  float b1a = b1[j0], b1b = b1[j0 + 1];
  float wma[10], wmb[10], bma[10], bmb[10];
#pragma unroll
  for (int e = 0; e < 10; e++) {
    float2 wmv = *(const float2*)(Wmeta + e * HD + j0);
    float2 bmv = *(const float2*)(bmeta + e * HD + j0);
    wma[e] = wmv.x; wmb[e] = wmv.y; bma[e] = bmv.x; bmb[e] = bmv.y;
  }
  for (int i = t; i < 64 * 12; i += 512) xs[i] = x[(size_t)r0 * 12 + i];
  __syncthreads();
  for (int r = 0; r < 64; r++) {
    const float* xr = xs + r * 12;
    float delta = xr[10], phi = xr[11];
    float s1a = 0.f, s1b = 0.f, s2a = 0.f, s2b = 0.f;
#pragma unroll
    for (int e = 0; e < 10; e++) {
      float oh = xr[e];
      s1a = fmaf(oh, wma[e], s1a);
      s1b = fmaf(oh, wmb[e], s1b);
      s2a = fmaf(oh, bma[e], s2a);
      s2b = fmaf(oh, bmb[e], s2b);
    }
    float pa = fmaf(delta, w1a, b1a) + fmaf(phi, s1a, s2a);
    float pb = fmaf(delta, w1b, b1b) + fmaf(phi, s1b, s2b);
    pa = fmaxf(pa, 0.f); pb = fmaxf(pb, 0.f);
    uint32_t pk = (uint32_t)f2bf(pa) | ((uint32_t)f2bf(pb) << 16);
    int rr = r0 + r;
    int g = j0 >> 3;
    int gs = (g & 124) | ((g & 3) ^ ((rr >> 1) & 3));
    *(uint32_t*)(h + (size_t)rr * HD + gs * 8 + (j0 & 7)) = pk;
  }
}

// ---------------- layers 2+3: R5 frame, B register-direct from packed L2, A via LDS ----------------
// grid 4096 (XCD-swizzled) = 512 rt x 8 ct; 256 threads = 4 waves (2x2), wave tile 64x64
// = 2x2 of 32x32x16 bf16 MFMA (acc 64 AGPR). LDS holds ONLY A (16 KB staging).
// Per K-tile(64): {8 B-frag global_load_dwordx4 -> regs (coalesced 1KB/wave from W2pk,
//   L2-resident 2MB) | 4 gl_lds A | __syncthreads (drains vmcnt: A in LDS + B in regs) |
//   8 ds_read_b128 (A frags) + 16 MFMA | __syncthreads}.
// Best-measured configuration (R13): k_gemm ~149 us = 922 TF = 37% of dense peak —
// the plain-HIP m97-class plateau; 11 structural variants (schedule, occupancy, LDS
// traffic, epilogue) all landed 154-292 us. 4 waves/SIMD is the hardware max for a
// 64-AGPR accumulator (unified need 124 regs; 512/124 = 4).
__global__ __launch_bounds__(256, 4) void k_gemm(
    const unsigned short* __restrict__ h, const unsigned short* __restrict__ W2pk,
    const float* __restrict__ b2, const float* __restrict__ W3,
    float* __restrict__ partial) {
  __shared__ char lds[34816];   // A panels @0/8192; epilogue reuses 33792 B
  int tid = threadIdx.x;
  // XCD swizzle: 4096 blocks = 8 XCDs x 512; XCD k gets contiguous logical range.
  int b = (int)blockIdx.x;
  int bx = ((b & 7) << 9) | (b >> 3);
  int rt = bx >> 3, ct = bx & 7;   // 8 consecutive bx share rt -> A-panel L2 reuse
  size_t r0 = (size_t)rt * 128;
  int c0 = ct * 128;
  int w = tid >> 6, lane = tid & 63;
  int wm = w >> 1, wn = w & 1;
  int l31 = lane & 31, hi = lane >> 5;
  int sw = (l31 >> 1) & 3;   // A granule swizzle key (row bases are multiples of 32)

  f32x16 acc[2][2];
#pragma unroll
  for (int rb = 0; rb < 2; rb++)
#pragma unroll
    for (int cb = 0; cb < 2; cb++)
#pragma unroll
      for (int i = 0; i < 16; i++) acc[rb][cb][i] = 0.f;

  int arow0 = (wm * 64 + 0  + l31) * 64;
  int arow1 = (wm * 64 + 32 + l31) * 64;
  // per-wave packed-B base for this ct: frags (cb,p,kl) at (cb*4+p*2+kl)*512 elements
  const unsigned short* bwave = W2pk + ((size_t)ct * 16 * 16 + (size_t)wn * 8) * 512 + lane * 8;

  for (int T = 0; T < 16; T++) {
    // 1) B fragments straight to registers (8 coalesced 1KB wave-loads, L2 hits)
    const unsigned short* bt = bwave + (size_t)T * 16 * 512;
    bf16x8 B[2][4];   // [cb][p*2+kl] — fully unrolled below -> register-resident
#pragma unroll
    for (int cb = 0; cb < 2; cb++)
#pragma unroll
      for (int pk = 0; pk < 4; pk++)
        B[cb][pk] = *(const bf16x8*)(bt + (cb * 4 + pk) * 512);
    // 2) stage A tile (panels p0@0, p1@8192; dest lane-linear; source pre-swizzled)
#pragma unroll
    for (int q = 0; q < 2; q++) {
      int s = tid + 256 * q;            // 0..511
      int row = s >> 2, g4 = s & 3;
      const unsigned short* hsrc = h + (r0 + row) * (size_t)HD + T * 64 + g4 * 8;
      gl16(hsrc,      lds +        (size_t)s * 16);
      gl16(hsrc + 32, lds + 8192 + (size_t)s * 16);
    }
    __syncthreads();   // drains vmcnt: A tile + B regs ready; prior A reads done
    // 3) A frag reads + MFMA (B from registers)
#pragma unroll
    for (int p = 0; p < 2; p++) {
      const char* lA = lds + p * 8192;
#pragma unroll
      for (int kl = 0; kl < 2; kl++) {
        int slot = ((kl * 2 + hi) ^ sw) << 4;
        bf16x8 a0 = *(const bf16x8*)(lA + arow0 + slot);
        bf16x8 a1 = *(const bf16x8*)(lA + arow1 + slot);
        acc[0][0] = __builtin_amdgcn_mfma_f32_32x32x16_bf16(a0, B[0][p * 2 + kl], acc[0][0], 0, 0, 0);
        acc[0][1] = __builtin_amdgcn_mfma_f32_32x32x16_bf16(a0, B[1][p * 2 + kl], acc[0][1], 0, 0, 0);
        acc[1][0] = __builtin_amdgcn_mfma_f32_32x32x16_bf16(a1, B[0][p * 2 + kl], acc[1][0], 0, 0, 0);
        acc[1][1] = __builtin_amdgcn_mfma_f32_32x32x16_bf16(a1, B[1][p * 2 + kl], acc[1][1], 0, 0, 0);
      }
    }
    __syncthreads();
  }

  // ---- epilogue: v = relu(acc+b2); o = v x W3^T; LDS transpose-reduce, coalesced writes ----
  float b2c[2], w30[2], w31[2];
#pragma unroll
  for (int cb = 0; cb < 2; cb++) {
    int c = c0 + wn * 64 + cb * 32 + l31;
    b2c[cb] = b2[c];
    w30[cb] = W3[c];
    w31[cb] = W3[HD + c];
  }
  // padded layout: line = (wm*32+rowf)*2 + wn in [0,128); float2 slot = line*33 + l31
  float2* sE = (float2*)lds;
#pragma unroll
  for (int rb = 0; rb < 2; rb++) {
    __syncthreads();
#pragma unroll
    for (int reg = 0; reg < 16; reg++) {
      float v0 = fmaxf(acc[rb][0][reg] + b2c[0], 0.f);
      float v1 = fmaxf(acc[rb][1][reg] + b2c[1], 0.f);
      float2 o;
      o.x = v0 * w30[0] + v1 * w30[1];
      o.y = v0 * w31[0] + v1 * w31[1];
      int rowf = (reg & 3) + 8 * (reg >> 2) + 4 * hi;   // verified C/D row map
      int line = (wm * 32 + rowf) * 2 + wn;
      sE[line * 33 + l31] = o;
    }
    __syncthreads();
    // reduce: 128 targets (bi 2 x rowf 32 x d 2), 2 threads each (half = wn index)
    int half = tid & 1, tgt = tid >> 1;
    int d = tgt & 1, rowf_t = (tgt >> 1) & 31, bi = tgt >> 6;
    int line0 = (bi * 32 + rowf_t) * 2 + half;
    const float* sf = (const float*)lds;
    float s = 0.f;
#pragma unroll
    for (int j = 0; j < 32; j++) s += sf[(line0 * 33 + j) * 2 + d];
    s += __shfl_xor(s, 1);
    if (half == 0) {
      int row = bi * 64 + rb * 32 + rowf_t;
      partial[(size_t)ct * (NROWS * 2) + (r0 + row) * 2 + d] = s;
    }
  }
}

// ---------------- final: out = b3 + sum over 8 col-tile partials ----------------
__global__ void k_reduce(const float* __restrict__ partial, const float* __restrict__ b3,
                         float* __restrict__ out) {
  int i = blockIdx.x * 256 + threadIdx.x;  // 131072
  float s = b3[i & 1];
#pragma unroll
  for (int ctt = 0; ctt < 8; ctt++) s += partial[(size_t)ctt * 131072 + i];
  out[i] = s;
}

extern "C" void kernel_launch(void* const* d_in, const int* in_sizes, int n_in,
                              void* d_out, int out_size, void* d_ws, size_t ws_size,
                              hipStream_t stream) {
  const float* x     = (const float*)d_in[0];
  const float* W1    = (const float*)d_in[1];
  const float* b1    = (const float*)d_in[2];
  const float* Wmeta = (const float*)d_in[3];
  const float* bmeta = (const float*)d_in[4];
  const float* W2    = (const float*)d_in[5];
  const float* b2    = (const float*)d_in[6];
  const float* W3    = (const float*)d_in[7];
  const float* b3    = (const float*)d_in[8];
  float* out = (float*)d_out;

  char* ws = (char*)d_ws;
  unsigned short* hbuf  = (unsigned short*)ws;                              // 128 MiB
  unsigned short* W2pk  = (unsigned short*)(ws + (size_t)NROWS * HD * 2);   // 2 MiB
  float* partial = (float*)(ws + (size_t)NROWS * HD * 2 + (size_t)HD * HD * 2);  // 4 MiB (8 slices)

  k_w2pk<<<512, 256, 0, stream>>>(W2, W2pk);
  k_layer1<<<1024, 512, 0, stream>>>(x, W1, b1, Wmeta, bmeta, hbuf);
  k_gemm<<<4096, 256, 0, stream>>>(hbuf, W2pk, b2, W3, partial);
  k_reduce<<<512, 256, 0, stream>>>(partial, b3, out);
}

// Round 21
// 198.250 us; speedup vs baseline: 13.2335x; 1.0400x over previous
//
#include <hip/hip_runtime.h>
#include <stdint.h>

#define NROWS 65536
#define HD 1024

typedef __attribute__((ext_vector_type(8))) short bf16x8;   // 8 bf16 in 4 VGPRs
typedef __attribute__((ext_vector_type(16))) float f32x16;  // MFMA 32x32 accumulator

typedef __attribute__((address_space(1))) const unsigned int* gas_ptr;
typedef __attribute__((address_space(3))) unsigned int* las_ptr;

__device__ __forceinline__ unsigned short f2bf(float f) {
  union { float f; uint32_t u; } v; v.f = f;
  uint32_t u = v.u;
  return (unsigned short)((u + 0x7fffu + ((u >> 16) & 1u)) >> 16);  // RNE
}

__device__ __forceinline__ void gl16(const void* g, void* l) {
  __builtin_amdgcn_global_load_lds((gas_ptr)g, (las_ptr)l, 16, 0, 0);
}

// ---------------- merged prep ----------------
// blocks 0-255:    pack W2 into MFMA-fragment order (R13 layout)
// blocks 256-1279: layer 1 -> h bf16 [65536][1024], granule swizzle (g&3)^((row>>1)&3),
//                  4 cols/thread -> 8B uint2 stores (G13: 8-16B/lane sweet spot)
// W2pk granule i: lane=i&63, f=(i>>6)&15 (f=wn*8+cb*4+p*2+kl), T=(i>>10)&15, ct=i>>14.
// col = ct*128+wn*64+cb*32+(lane&31); k = T*64+p*32+kl*16+(lane>>5)*8.
__global__ __launch_bounds__(512) void k_prep(
    const float* __restrict__ x, const float* __restrict__ W1,
    const float* __restrict__ b1, const float* __restrict__ Wmeta,
    const float* __restrict__ bmeta, const float* __restrict__ W2,
    unsigned short* __restrict__ h, unsigned short* __restrict__ W2pk) {
  __shared__ float xs[64 * 12];
  if (blockIdx.x < 256) {   // ---- W2 fragment packing ----
    int i = blockIdx.x * 512 + threadIdx.x;      // 131072 granules
    int lane = i & 63, f = (i >> 6) & 15, T = (i >> 10) & 15, ct = i >> 14;
    int kl = f & 1, p = (f >> 1) & 1, cb = (f >> 2) & 1, wn = f >> 3;
    int col = ct * 128 + wn * 64 + cb * 32 + (lane & 31);
    int k = T * 64 + p * 32 + kl * 16 + (lane >> 5) * 8;
    const float4* s4 = (const float4*)(W2 + (size_t)col * HD + k);
    float4 a = s4[0], b = s4[1];
    uint4 pk;
    pk.x = (uint32_t)f2bf(a.x) | ((uint32_t)f2bf(a.y) << 16);
    pk.y = (uint32_t)f2bf(a.z) | ((uint32_t)f2bf(a.w) << 16);
    pk.z = (uint32_t)f2bf(b.x) | ((uint32_t)f2bf(b.y) << 16);
    pk.w = (uint32_t)f2bf(b.z) | ((uint32_t)f2bf(b.w) << 16);
    *(uint4*)(W2pk + (size_t)i * 8) = pk;
    return;
  }
  // ---- layer 1: h = relu(delta*W1 + b1 + phi*(oh@Wmeta) + oh@bmeta) ----
  // block = 64 rows; thread t: rows rp*2 + (t>>8), cols j0=(t&255)*4 .. +3.
  int r0 = ((int)blockIdx.x - 256) * 64;
  int t = threadIdx.x;
  int rset = t >> 8;                 // 0/1: which row of each pair
  int j0 = (t & 255) * 4;            // col base (4-aligned)
  float w1v[4], b1v[4], wm[10][4], bm[10][4];
#pragma unroll
  for (int c = 0; c < 4; c++) { w1v[c] = W1[j0 + c]; b1v[c] = b1[j0 + c]; }
#pragma unroll
  for (int e = 0; e < 10; e++) {
    float4 wmv = *(const float4*)(Wmeta + e * HD + j0);
    float4 bmv = *(const float4*)(bmeta + e * HD + j0);
    wm[e][0] = wmv.x; wm[e][1] = wmv.y; wm[e][2] = wmv.z; wm[e][3] = wmv.w;
    bm[e][0] = bmv.x; bm[e][1] = bmv.y; bm[e][2] = bmv.z; bm[e][3] = bmv.w;
  }
  for (int i = t; i < 64 * 12; i += 512) xs[i] = x[(size_t)r0 * 12 + i];
  __syncthreads();
  int g = j0 >> 3;
  for (int rp = 0; rp < 32; rp++) {
    int r = rp * 2 + rset;
    const float* xr = xs + r * 12;
    float delta = xr[10], phi = xr[11];
    float s1[4] = {0.f, 0.f, 0.f, 0.f}, s2[4] = {0.f, 0.f, 0.f, 0.f};
#pragma unroll
    for (int e = 0; e < 10; e++) {
      float oh = xr[e];
#pragma unroll
      for (int c = 0; c < 4; c++) {
        s1[c] = fmaf(oh, wm[e][c], s1[c]);
        s2[c] = fmaf(oh, bm[e][c], s2[c]);
      }
    }
    float p[4];
#pragma unroll
    for (int c = 0; c < 4; c++)
      p[c] = fmaxf(fmaf(delta, w1v[c], b1v[c]) + fmaf(phi, s1[c], s2[c]), 0.f);
    uint2 v;
    v.x = (uint32_t)f2bf(p[0]) | ((uint32_t)f2bf(p[1]) << 16);
    v.y = (uint32_t)f2bf(p[2]) | ((uint32_t)f2bf(p[3]) << 16);
    int rr = r0 + r;
    int gs = (g & 124) | ((g & 3) ^ ((rr >> 1) & 3));
    *(uint2*)(h + (size_t)rr * HD + gs * 8 + (j0 & 7)) = v;   // 8B store
  }
}

// ---------------- layers 2+3: R13/R20 main loop verbatim (best-measured: ~149 us) ----------------
// grid 4096 (XCD-swizzled) = 512 rt x 8 ct; 256 threads = 4 waves (2x2), wave tile 64x64
// = 2x2 of 32x32x16 bf16 MFMA (acc 64 AGPR). LDS holds ONLY A (16 KB staging).
// Per K-tile(64): {8 B-frag global_load_dwordx4 -> regs (coalesced 1KB/wave from W2pk,
//   L2-resident 2MB) | 4 gl_lds A | __syncthreads | 8 ds_read_b128 + 16 MFMA | __syncthreads}.
// 922 TF = 37% of dense peak — plain-HIP m97-class plateau; 11 structural variants
// (schedule, occupancy, LDS traffic, epilogue) all landed 154-292 us. 4 waves/SIMD is
// the hardware max for a 64-AGPR accumulator (unified need 124 regs; 512/124 = 4).
__global__ __launch_bounds__(256, 4) void k_gemm(
    const unsigned short* __restrict__ h, const unsigned short* __restrict__ W2pk,
    const float* __restrict__ b2, const float* __restrict__ W3,
    float* __restrict__ partial) {
  __shared__ char lds[34816];   // A panels @0/8192; epilogue reuses 33792 B
  int tid = threadIdx.x;
  // XCD swizzle: 4096 blocks = 8 XCDs x 512; XCD k gets contiguous logical range.
  int b = (int)blockIdx.x;
  int bx = ((b & 7) << 9) | (b >> 3);
  int rt = bx >> 3, ct = bx & 7;   // 8 consecutive bx share rt -> A-panel L2 reuse
  size_t r0 = (size_t)rt * 128;
  int c0 = ct * 128;
  int w = tid >> 6, lane = tid & 63;
  int wm = w >> 1, wn = w & 1;
  int l31 = lane & 31, hi = lane >> 5;
  int sw = (l31 >> 1) & 3;   // A granule swizzle key (row bases are multiples of 32)

  f32x16 acc[2][2];
#pragma unroll
  for (int rb = 0; rb < 2; rb++)
#pragma unroll
    for (int cb = 0; cb < 2; cb++)
#pragma unroll
      for (int i = 0; i < 16; i++) acc[rb][cb][i] = 0.f;

  int arow0 = (wm * 64 + 0  + l31) * 64;
  int arow1 = (wm * 64 + 32 + l31) * 64;
  // per-wave packed-B base for this ct: frags (cb,p,kl) at (cb*4+p*2+kl)*512 elements
  const unsigned short* bwave = W2pk + ((size_t)ct * 16 * 16 + (size_t)wn * 8) * 512 + lane * 8;

  for (int T = 0; T < 16; T++) {
    // 1) B fragments straight to registers (8 coalesced 1KB wave-loads, L2 hits)
    const unsigned short* bt = bwave + (size_t)T * 16 * 512;
    bf16x8 B[2][4];   // [cb][p*2+kl] — fully unrolled below -> register-resident
#pragma unroll
    for (int cb = 0; cb < 2; cb++)
#pragma unroll
      for (int pk = 0; pk < 4; pk++)
        B[cb][pk] = *(const bf16x8*)(bt + (cb * 4 + pk) * 512);
    // 2) stage A tile (panels p0@0, p1@8192; dest lane-linear; source pre-swizzled)
#pragma unroll
    for (int q = 0; q < 2; q++) {
      int s = tid + 256 * q;            // 0..511
      int row = s >> 2, g4 = s & 3;
      const unsigned short* hsrc = h + (r0 + row) * (size_t)HD + T * 64 + g4 * 8;
      gl16(hsrc,      lds +        (size_t)s * 16);
      gl16(hsrc + 32, lds + 8192 + (size_t)s * 16);
    }
    __syncthreads();   // drains vmcnt: A tile + B regs ready; prior A reads done
    // 3) A frag reads + MFMA (B from registers)
#pragma unroll
    for (int p = 0; p < 2; p++) {
      const char* lA = lds + p * 8192;
#pragma unroll
      for (int kl = 0; kl < 2; kl++) {
        int slot = ((kl * 2 + hi) ^ sw) << 4;
        bf16x8 a0 = *(const bf16x8*)(lA + arow0 + slot);
        bf16x8 a1 = *(const bf16x8*)(lA + arow1 + slot);
        acc[0][0] = __builtin_amdgcn_mfma_f32_32x32x16_bf16(a0, B[0][p * 2 + kl], acc[0][0], 0, 0, 0);
        acc[0][1] = __builtin_amdgcn_mfma_f32_32x32x16_bf16(a0, B[1][p * 2 + kl], acc[0][1], 0, 0, 0);
        acc[1][0] = __builtin_amdgcn_mfma_f32_32x32x16_bf16(a1, B[0][p * 2 + kl], acc[1][0], 0, 0, 0);
        acc[1][1] = __builtin_amdgcn_mfma_f32_32x32x16_bf16(a1, B[1][p * 2 + kl], acc[1][1], 0, 0, 0);
      }
    }
    __syncthreads();
  }

  // ---- epilogue: v = relu(acc+b2); o = v x W3^T; LDS transpose-reduce, coalesced writes ----
  float b2c[2], w30[2], w31[2];
#pragma unroll
  for (int cb = 0; cb < 2; cb++) {
    int c = c0 + wn * 64 + cb * 32 + l31;
    b2c[cb] = b2[c];
    w30[cb] = W3[c];
    w31[cb] = W3[HD + c];
  }
  // padded layout: line = (wm*32+rowf)*2 + wn in [0,128); float2 slot = line*33 + l31
  float2* sE = (float2*)lds;
#pragma unroll
  for (int rb = 0; rb < 2; rb++) {
    __syncthreads();
#pragma unroll
    for (int reg = 0; reg < 16; reg++) {
      float v0 = fmaxf(acc[rb][0][reg] + b2c[0], 0.f);
      float v1 = fmaxf(acc[rb][1][reg] + b2c[1], 0.f);
      float2 o;
      o.x = v0 * w30[0] + v1 * w30[1];
      o.y = v0 * w31[0] + v1 * w31[1];
      int rowf = (reg & 3) + 8 * (reg >> 2) + 4 * hi;   // verified C/D row map
      int line = (wm * 32 + rowf) * 2 + wn;
      sE[line * 33 + l31] = o;
    }
    __syncthreads();
    // reduce: 128 targets (bi 2 x rowf 32 x d 2), 2 threads each (half = wn index)
    int half = tid & 1, tgt = tid >> 1;
    int d = tgt & 1, rowf_t = (tgt >> 1) & 31, bi = tgt >> 6;
    int line0 = (bi * 32 + rowf_t) * 2 + half;
    const float* sf = (const float*)lds;
    float s = 0.f;
#pragma unroll
    for (int j = 0; j < 32; j++) s += sf[(line0 * 33 + j) * 2 + d];
    s += __shfl_xor(s, 1);
    if (half == 0) {
      int row = bi * 64 + rb * 32 + rowf_t;
      partial[(size_t)ct * (NROWS * 2) + (r0 + row) * 2 + d] = s;
    }
  }
}

// ---------------- final: out = b3 + sum over 8 col-tile partials ----------------
__global__ void k_reduce(const float* __restrict__ partial, const float* __restrict__ b3,
                         float* __restrict__ out) {
  int i = blockIdx.x * 256 + threadIdx.x;  // 131072
  float s = b3[i & 1];
#pragma unroll
  for (int ctt = 0; ctt < 8; ctt++) s += partial[(size_t)ctt * 131072 + i];
  out[i] = s;
}

extern "C" void kernel_launch(void* const* d_in, const int* in_sizes, int n_in,
                              void* d_out, int out_size, void* d_ws, size_t ws_size,
                              hipStream_t stream) {
  const float* x     = (const float*)d_in[0];
  const float* W1    = (const float*)d_in[1];
  const float* b1    = (const float*)d_in[2];
  const float* Wmeta = (const float*)d_in[3];
  const float* bmeta = (const float*)d_in[4];
  const float* W2    = (const float*)d_in[5];
  const float* b2    = (const float*)d_in[6];
  const float* W3    = (const float*)d_in[7];
  const float* b3    = (const float*)d_in[8];
  float* out = (float*)d_out;

  char* ws = (char*)d_ws;
  unsigned short* hbuf  = (unsigned short*)ws;                              // 128 MiB
  unsigned short* W2pk  = (unsigned short*)(ws + (size_t)NROWS * HD * 2);   // 2 MiB
  float* partial = (float*)(ws + (size_t)NROWS * HD * 2 + (size_t)HD * HD * 2);  // 4 MiB (8 slices)

  k_prep<<<1280, 512, 0, stream>>>(x, W1, b1, Wmeta, bmeta, W2, hbuf, W2pk);
  k_gemm<<<4096, 256, 0, stream>>>(hbuf, W2pk, b2, W3, partial);
  k_reduce<<<512, 256, 0, stream>>>(partial, b3, out);
}

// Round 22
// 196.177 us; speedup vs baseline: 13.3733x; 1.0106x over previous
//
#include <hip/hip_runtime.h>
#include <stdint.h>

#define NROWS 65536
#define HD 1024

typedef __attribute__((ext_vector_type(8))) short bf16x8;   // 8 bf16 in 4 VGPRs
typedef __attribute__((ext_vector_type(16))) float f32x16;  // MFMA 32x32 accumulator
typedef __attribute__((ext_vector_type(2))) float f32x2;    // packed fp32 (v_pk_fma_f32)

typedef __attribute__((address_space(1))) const unsigned int* gas_ptr;
typedef __attribute__((address_space(3))) unsigned int* las_ptr;

__device__ __forceinline__ unsigned short f2bf(float f) {
  union { float f; uint32_t u; } v; v.f = f;
  uint32_t u = v.u;
  return (unsigned short)((u + 0x7fffu + ((u >> 16) & 1u)) >> 16);  // RNE
}

__device__ __forceinline__ void gl16(const void* g, void* l) {
  __builtin_amdgcn_global_load_lds((gas_ptr)g, (las_ptr)l, 16, 0, 0);
}

// ---------------- merged prep ----------------
// blocks 0-255:    pack W2 into MFMA-fragment order (R13 layout)
// blocks 256-1279: layer 1 -> h bf16 [65536][1024], granule swizzle (g&3)^((row>>1)&3),
//                  4 cols/thread as 2x f32x2 (packed fp32 math) -> 8B uint2 stores
// W2pk granule i: lane=i&63, f=(i>>6)&15 (f=wn*8+cb*4+p*2+kl), T=(i>>10)&15, ct=i>>14.
// col = ct*128+wn*64+cb*32+(lane&31); k = T*64+p*32+kl*16+(lane>>5)*8.
__global__ __launch_bounds__(512) void k_prep(
    const float* __restrict__ x, const float* __restrict__ W1,
    const float* __restrict__ b1, const float* __restrict__ Wmeta,
    const float* __restrict__ bmeta, const float* __restrict__ W2,
    unsigned short* __restrict__ h, unsigned short* __restrict__ W2pk) {
  __shared__ float xs[64 * 12];
  if (blockIdx.x < 256) {   // ---- W2 fragment packing ----
    int i = blockIdx.x * 512 + threadIdx.x;      // 131072 granules
    int lane = i & 63, f = (i >> 6) & 15, T = (i >> 10) & 15, ct = i >> 14;
    int kl = f & 1, p = (f >> 1) & 1, cb = (f >> 2) & 1, wn = f >> 3;
    int col = ct * 128 + wn * 64 + cb * 32 + (lane & 31);
    int k = T * 64 + p * 32 + kl * 16 + (lane >> 5) * 8;
    const float4* s4 = (const float4*)(W2 + (size_t)col * HD + k);
    float4 a = s4[0], b = s4[1];
    uint4 pk;
    pk.x = (uint32_t)f2bf(a.x) | ((uint32_t)f2bf(a.y) << 16);
    pk.y = (uint32_t)f2bf(a.z) | ((uint32_t)f2bf(a.w) << 16);
    pk.z = (uint32_t)f2bf(b.x) | ((uint32_t)f2bf(b.y) << 16);
    pk.w = (uint32_t)f2bf(b.z) | ((uint32_t)f2bf(b.w) << 16);
    *(uint4*)(W2pk + (size_t)i * 8) = pk;
    return;
  }
  // ---- layer 1: h = relu(delta*W1 + b1 + phi*(oh@Wmeta) + oh@bmeta) ----
  // block = 64 rows; thread t: rows rp*2 + (t>>8), cols j0=(t&255)*4 .. +3.
  // Math on f32x2 so clang forms v_pk_fma_f32 (ffp-contract=fast default).
  int r0 = ((int)blockIdx.x - 256) * 64;
  int t = threadIdx.x;
  int rset = t >> 8;                 // 0/1: which row of each pair
  int j0 = (t & 255) * 4;            // col base (4-aligned)
  f32x2 w1v[2], b1v[2], wm[10][2], bm[10][2];
  {
    float4 a = *(const float4*)(W1 + j0);
    float4 c = *(const float4*)(b1 + j0);
    w1v[0] = (f32x2){a.x, a.y}; w1v[1] = (f32x2){a.z, a.w};
    b1v[0] = (f32x2){c.x, c.y}; b1v[1] = (f32x2){c.z, c.w};
  }
#pragma unroll
  for (int e = 0; e < 10; e++) {
    float4 wmv = *(const float4*)(Wmeta + e * HD + j0);
    float4 bmv = *(const float4*)(bmeta + e * HD + j0);
    wm[e][0] = (f32x2){wmv.x, wmv.y}; wm[e][1] = (f32x2){wmv.z, wmv.w};
    bm[e][0] = (f32x2){bmv.x, bmv.y}; bm[e][1] = (f32x2){bmv.z, bmv.w};
  }
  for (int i = t; i < 64 * 12; i += 512) xs[i] = x[(size_t)r0 * 12 + i];
  __syncthreads();
  int g = j0 >> 3;
  for (int rp = 0; rp < 32; rp++) {
    int r = rp * 2 + rset;
    const float* xr = xs + r * 12;
    float delta = xr[10], phi = xr[11];
    f32x2 s1a = (f32x2){0.f, 0.f}, s1b = s1a, s2a = s1a, s2b = s1a;
#pragma unroll
    for (int e = 0; e < 10; e++) {
      float oh = xr[e];
      s1a += oh * wm[e][0];
      s1b += oh * wm[e][1];
      s2a += oh * bm[e][0];
      s2b += oh * bm[e][1];
    }
    f32x2 pa = delta * w1v[0] + b1v[0] + phi * s1a + s2a;
    f32x2 pb = delta * w1v[1] + b1v[1] + phi * s1b + s2b;
    float p0 = fmaxf(pa[0], 0.f), p1 = fmaxf(pa[1], 0.f);
    float p2 = fmaxf(pb[0], 0.f), p3 = fmaxf(pb[1], 0.f);
    uint2 v;
    v.x = (uint32_t)f2bf(p0) | ((uint32_t)f2bf(p1) << 16);
    v.y = (uint32_t)f2bf(p2) | ((uint32_t)f2bf(p3) << 16);
    int rr = r0 + r;
    int gs = (g & 124) | ((g & 3) ^ ((rr >> 1) & 3));
    *(uint2*)(h + (size_t)rr * HD + gs * 8 + (j0 & 7)) = v;   // 8B store
  }
}

// ---------------- layers 2+3: R13/R20 main loop verbatim (best-measured: ~149 us) ----------------
// grid 4096 (XCD-swizzled) = 512 rt x 8 ct; 256 threads = 4 waves (2x2), wave tile 64x64
// = 2x2 of 32x32x16 bf16 MFMA (acc 64 AGPR). LDS holds ONLY A (16 KB staging).
// Per K-tile(64): {8 B-frag global_load_dwordx4 -> regs (coalesced 1KB/wave from W2pk,
//   L2-resident 2MB) | 4 gl_lds A | __syncthreads | 8 ds_read_b128 + 16 MFMA | __syncthreads}.
// 922 TF = 37% of dense peak — plain-HIP m97-class plateau; 11 structural variants
// (schedule, occupancy, LDS traffic, epilogue) all landed 154-292 us. 4 waves/SIMD is
// the hardware max for a 64-AGPR accumulator (unified need 124 regs; 512/124 = 4).
__global__ __launch_bounds__(256, 4) void k_gemm(
    const unsigned short* __restrict__ h, const unsigned short* __restrict__ W2pk,
    const float* __restrict__ b2, const float* __restrict__ W3,
    float* __restrict__ partial) {
  __shared__ char lds[34816];   // A panels @0/8192; epilogue reuses 33792 B
  int tid = threadIdx.x;
  // XCD swizzle: 4096 blocks = 8 XCDs x 512; XCD k gets contiguous logical range.
  int b = (int)blockIdx.x;
  int bx = ((b & 7) << 9) | (b >> 3);
  int rt = bx >> 3, ct = bx & 7;   // 8 consecutive bx share rt -> A-panel L2 reuse
  size_t r0 = (size_t)rt * 128;
  int c0 = ct * 128;
  int w = tid >> 6, lane = tid & 63;
  int wm = w >> 1, wn = w & 1;
  int l31 = lane & 31, hi = lane >> 5;
  int sw = (l31 >> 1) & 3;   // A granule swizzle key (row bases are multiples of 32)

  f32x16 acc[2][2];
#pragma unroll
  for (int rb = 0; rb < 2; rb++)
#pragma unroll
    for (int cb = 0; cb < 2; cb++)
#pragma unroll
      for (int i = 0; i < 16; i++) acc[rb][cb][i] = 0.f;

  int arow0 = (wm * 64 + 0  + l31) * 64;
  int arow1 = (wm * 64 + 32 + l31) * 64;
  // per-wave packed-B base for this ct: frags (cb,p,kl) at (cb*4+p*2+kl)*512 elements
  const unsigned short* bwave = W2pk + ((size_t)ct * 16 * 16 + (size_t)wn * 8) * 512 + lane * 8;

  for (int T = 0; T < 16; T++) {
    // 1) B fragments straight to registers (8 coalesced 1KB wave-loads, L2 hits)
    const unsigned short* bt = bwave + (size_t)T * 16 * 512;
    bf16x8 B[2][4];   // [cb][p*2+kl] — fully unrolled below -> register-resident
#pragma unroll
    for (int cb = 0; cb < 2; cb++)
#pragma unroll
      for (int pk = 0; pk < 4; pk++)
        B[cb][pk] = *(const bf16x8*)(bt + (cb * 4 + pk) * 512);
    // 2) stage A tile (panels p0@0, p1@8192; dest lane-linear; source pre-swizzled)
#pragma unroll
    for (int q = 0; q < 2; q++) {
      int s = tid + 256 * q;            // 0..511
      int row = s >> 2, g4 = s & 3;
      const unsigned short* hsrc = h + (r0 + row) * (size_t)HD + T * 64 + g4 * 8;
      gl16(hsrc,      lds +        (size_t)s * 16);
      gl16(hsrc + 32, lds + 8192 + (size_t)s * 16);
    }
    __syncthreads();   // drains vmcnt: A tile + B regs ready; prior A reads done
    // 3) A frag reads + MFMA (B from registers)
#pragma unroll
    for (int p = 0; p < 2; p++) {
      const char* lA = lds + p * 8192;
#pragma unroll
      for (int kl = 0; kl < 2; kl++) {
        int slot = ((kl * 2 + hi) ^ sw) << 4;
        bf16x8 a0 = *(const bf16x8*)(lA + arow0 + slot);
        bf16x8 a1 = *(const bf16x8*)(lA + arow1 + slot);
        acc[0][0] = __builtin_amdgcn_mfma_f32_32x32x16_bf16(a0, B[0][p * 2 + kl], acc[0][0], 0, 0, 0);
        acc[0][1] = __builtin_amdgcn_mfma_f32_32x32x16_bf16(a0, B[1][p * 2 + kl], acc[0][1], 0, 0, 0);
        acc[1][0] = __builtin_amdgcn_mfma_f32_32x32x16_bf16(a1, B[0][p * 2 + kl], acc[1][0], 0, 0, 0);
        acc[1][1] = __builtin_amdgcn_mfma_f32_32x32x16_bf16(a1, B[1][p * 2 + kl], acc[1][1], 0, 0, 0);
      }
    }
    __syncthreads();
  }

  // ---- epilogue: v = relu(acc+b2); o = v x W3^T; LDS transpose-reduce, coalesced writes ----
  float b2c[2], w30[2], w31[2];
#pragma unroll
  for (int cb = 0; cb < 2; cb++) {
    int c = c0 + wn * 64 + cb * 32 + l31;
    b2c[cb] = b2[c];
    w30[cb] = W3[c];
    w31[cb] = W3[HD + c];
  }
  // padded layout: line = (wm*32+rowf)*2 + wn in [0,128); float2 slot = line*33 + l31
  float2* sE = (float2*)lds;
#pragma unroll
  for (int rb = 0; rb < 2; rb++) {
    __syncthreads();
#pragma unroll
    for (int reg = 0; reg < 16; reg++) {
      float v0 = fmaxf(acc[rb][0][reg] + b2c[0], 0.f);
      float v1 = fmaxf(acc[rb][1][reg] + b2c[1], 0.f);
      float2 o;
      o.x = v0 * w30[0] + v1 * w30[1];
      o.y = v0 * w31[0] + v1 * w31[1];
      int rowf = (reg & 3) + 8 * (reg >> 2) + 4 * hi;   // verified C/D row map
      int line = (wm * 32 + rowf) * 2 + wn;
      sE[line * 33 + l31] = o;
    }
    __syncthreads();
    // reduce: 128 targets (bi 2 x rowf 32 x d 2), 2 threads each (half = wn index)
    int half = tid & 1, tgt = tid >> 1;
    int d = tgt & 1, rowf_t = (tgt >> 1) & 31, bi = tgt >> 6;
    int line0 = (bi * 32 + rowf_t) * 2 + half;
    const float* sf = (const float*)lds;
    float s = 0.f;
#pragma unroll
    for (int j = 0; j < 32; j++) s += sf[(line0 * 33 + j) * 2 + d];
    s += __shfl_xor(s, 1);
    if (half == 0) {
      int row = bi * 64 + rb * 32 + rowf_t;
      partial[(size_t)ct * (NROWS * 2) + (r0 + row) * 2 + d] = s;
    }
  }
}

// ---------------- final: out = b3 + sum over 8 col-tile partials ----------------
__global__ void k_reduce(const float* __restrict__ partial, const float* __restrict__ b3,
                         float* __restrict__ out) {
  int i = blockIdx.x * 256 + threadIdx.x;  // 131072
  float s = b3[i & 1];
#pragma unroll
  for (int ctt = 0; ctt < 8; ctt++) s += partial[(size_t)ctt * 131072 + i];
  out[i] = s;
}

extern "C" void kernel_launch(void* const* d_in, const int* in_sizes, int n_in,
                              void* d_out, int out_size, void* d_ws, size_t ws_size,
                              hipStream_t stream) {
  const float* x     = (const float*)d_in[0];
  const float* W1    = (const float*)d_in[1];
  const float* b1    = (const float*)d_in[2];
  const float* Wmeta = (const float*)d_in[3];
  const float* bmeta = (const float*)d_in[4];
  const float* W2    = (const float*)d_in[5];
  const float* b2    = (const float*)d_in[6];
  const float* W3    = (const float*)d_in[7];
  const float* b3    = (const float*)d_in[8];
  float* out = (float*)d_out;

  char* ws = (char*)d_ws;
  unsigned short* hbuf  = (unsigned short*)ws;                              // 128 MiB
  unsigned short* W2pk  = (unsigned short*)(ws + (size_t)NROWS * HD * 2);   // 2 MiB
  float* partial = (float*)(ws + (size_t)NROWS * HD * 2 + (size_t)HD * HD * 2);  // 4 MiB (8 slices)

  k_prep<<<1280, 512, 0, stream>>>(x, W1, b1, Wmeta, bmeta, W2, hbuf, W2pk);
  k_gemm<<<4096, 256, 0, stream>>>(hbuf, W2pk, b2, W3, partial);
  k_reduce<<<512, 256, 0, stream>>>(partial, b3, out);
}